// Round 11
// baseline (243.732 us; speedup 1.0000x reference)
//
#include <hip/hip_runtime.h>
#include <math.h>

#define BATCH 524288
#define VEC 512
#define TPR 128  // threads per row: each thread produces 2 (sin,cos) pairs = 1 float4

typedef float f32x4 __attribute__((ext_vector_type(4)));

// Accurate sincos of an f32 phase value: f64 reduction by pi/2 of the exact
// f32 input, then f32 minimax kernels on [-pi/4, pi/4] (~1e-7 abs error).
// (R2==R6 and R3==R5 bit-identical absmax proved sin impl is NOT the error
// source; all observed error was in the frequency values.)
__device__ __forceinline__ void sincos_acc(float phf, float& s, float& c) {
    const double two_over_pi = 0.6366197723675814;
    const double pio2        = 1.5707963267948966;
    const double ph  = (double)phf;                 // exact
    const double nd  = rint(ph * two_over_pi);      // |nd| <= ~3.4e4, exact int
    const double red = fma(-nd, pio2, ph);          // |red| <= pi/4, err ~1e-12
    const int    q   = ((int)nd) & 3;               // correct for negative nd
    const float  r   = (float)red;
    const float  r2  = r * r;
    float sp = fmaf(r2, 2.7183114939898219e-6f, -1.9839334836096632e-4f);
    sp = fmaf(r2, sp, 8.3333293858894632e-3f);
    sp = fmaf(r2, sp, -1.6666666641626524e-1f);
    sp = r * fmaf(r2, sp, 1.0f);
    float cp = fmaf(r2, 2.4390448796277409e-5f, -1.3886763774609929e-3f);
    cp = fmaf(r2, cp, 4.1666623323739063e-2f);
    cp = fmaf(r2, cp, -4.9999999725103100e-1f);
    cp = fmaf(r2, cp, 1.0f);
    const bool swp = (q & 1);
    float ss = swp ? cp : sp;
    float cc = swp ? sp : cp;
    s = (q & 2)       ? -ss : ss;
    c = ((q + 1) & 2) ? -cc : cc;
}

__global__ __launch_bounds__(256) void input_layer_kernel(const float* __restrict__ x,
                                                          float* __restrict__ out) {
    const int t = blockIdx.x * blockDim.x + threadIdx.x;
    const int q = t & (TPR - 1);         // which float4 within the row: 0..127
    const int row0 = t >> 7;             // starting row
    const int rows_per_step = (gridDim.x * blockDim.x) >> 7;

    // FREQUENCY CHAIN -- correctness-critical, verified round 10 (absmax 3.9e-3):
    // ref e-chain = fast-math reciprocal division (XLA:CPU arcp):
    //   e = (i * fl32(1/255)) * 4, NOT true f32 division.
    // pow = accurate exp10 (<=1 ulp from CR) -> matched by CR f64 pow.
    // DO NOT change these lines.
    const float RCP255 = 1.0f / 255.0f;                 // compile-time fl32(1/255)
    const float e0 = ((float)(2 * q)     * RCP255) * 4.0f;
    const float e1 = ((float)(2 * q + 1) * RCP255) * 4.0f;
    const float f0 = (float)pow(10.0, (double)e0);      // CR pow == CR powf
    const float f1 = (float)pow(10.0, (double)e1);

    for (int row = row0; row < BATCH; row += rows_per_step) {
        const float xv = x[row];
        float s0, c0, s1, c1;
        sincos_acc(xv * f0, s0, c0);     // phase rounded to f32, like the ref
        sincos_acc(xv * f1, s1, c1);
        // out[row, 4q .. 4q+3] = {sin(2q), cos(2q), sin(2q+1), cos(2q+1)}
        f32x4 o = {s0, c0, s1, c1};
        // A/B vs round 10: REGULAR cached store (no nontemporal flag).
        // Theory: NT (sc0/sc1/nt) bypasses the L2 write-combine path that
        // lets fillBuffer hit 6.6 TB/s; we measured only 5.0 TB/s with NT.
        f32x4* dst = reinterpret_cast<f32x4*>(out + (size_t)row * VEC) + q;
        *dst = o;
    }
}

extern "C" void kernel_launch(void* const* d_in, const int* in_sizes, int n_in,
                              void* d_out, int out_size, void* d_ws, size_t ws_size,
                              hipStream_t stream) {
    const float* x = (const float*)d_in[0];
    float* out = (float*)d_out;
    // 2048 blocks x 256 threads = 4096 rows per grid step, 128 grid-stride steps.
    input_layer_kernel<<<2048, 256, 0, stream>>>(x, out);
}

// Round 12
// 201.466 us; speedup vs baseline: 1.2098x; 1.2098x over previous
//
#include <hip/hip_runtime.h>
#include <math.h>

#define BATCH 524288
#define VEC 512
#define RPB 128   // contiguous rows per block; 4096 blocks x 128 rows = 524288

typedef float f32x4 __attribute__((ext_vector_type(4)));

// Accurate sincos of an f32 phase value: f64 reduction by pi/2 of the exact
// f32 input, then f32 minimax kernels on [-pi/4, pi/4] (~1e-7 abs error).
// Correctness-proven in round 10 (absmax 3.9e-3). DO NOT change.
__device__ __forceinline__ void sincos_acc(float phf, float& s, float& c) {
    const double two_over_pi = 0.6366197723675814;
    const double pio2        = 1.5707963267948966;
    const double ph  = (double)phf;                 // exact
    const double nd  = rint(ph * two_over_pi);      // |nd| <= ~3.4e4, exact int
    const double red = fma(-nd, pio2, ph);          // |red| <= pi/4, err ~1e-12
    const int    q   = ((int)nd) & 3;               // correct for negative nd
    const float  r   = (float)red;
    const float  r2  = r * r;
    float sp = fmaf(r2, 2.7183114939898219e-6f, -1.9839334836096632e-4f);
    sp = fmaf(r2, sp, 8.3333293858894632e-3f);
    sp = fmaf(r2, sp, -1.6666666641626524e-1f);
    sp = r * fmaf(r2, sp, 1.0f);
    float cp = fmaf(r2, 2.4390448796277409e-5f, -1.3886763774609929e-3f);
    cp = fmaf(r2, cp, 4.1666623323739063e-2f);
    cp = fmaf(r2, cp, -4.9999999725103100e-1f);
    cp = fmaf(r2, cp, 1.0f);
    const bool swp = (q & 1);
    float ss = swp ? cp : sp;
    float cc = swp ? sp : cp;
    s = (q & 2)       ? -ss : ss;
    c = ((q + 1) & 2) ? -cc : cc;
}

__global__ __launch_bounds__(256) void input_layer_kernel(const float* __restrict__ x,
                                                          float* __restrict__ out) {
    __shared__ float xs[RPB];
    const int tid  = threadIdx.x;
    const int base = blockIdx.x * RPB;          // this block's contiguous row range

    // One-time x stage: 128 floats = 512 B coalesced. After this, the hot
    // loop does ZERO global reads -- pure write stream like fillBuffer
    // (theory: x reads interleaving with the NT write stream caused HBM
    // read/write turnarounds = the 5.0 vs 6.6 TB/s gap).
    if (tid < RPB) xs[tid] = x[base + tid];

    // FREQUENCY CHAIN -- correctness-critical, verified round 10 (absmax 3.9e-3):
    // ref e-chain = fast-math reciprocal division (XLA:CPU arcp):
    //   e = (i * fl32(1/255)) * 4, NOT true f32 division.
    // pow = accurate exp10 -> matched by CR f64 pow. DO NOT change.
    const int   q      = tid & 127;             // float4 index within row
    const float RCP255 = 1.0f / 255.0f;         // compile-time fl32(1/255)
    const float e0 = ((float)(2 * q)     * RCP255) * 4.0f;
    const float e1 = ((float)(2 * q + 1) * RCP255) * 4.0f;
    const float f0 = (float)pow(10.0, (double)e0);
    const float f1 = (float)pow(10.0, (double)e1);

    __syncthreads();

    const int half = tid >> 7;                  // 0 or 1: which of the 2 rows/iter
    for (int k = 0; k < RPB; k += 2) {
        const int   r  = k + half;              // wave-uniform -> LDS broadcast read
        const float xv = xs[r];
        float s0, c0, s1, c1;
        sincos_acc(xv * f0, s0, c0);            // phase rounded to f32, like the ref
        sincos_acc(xv * f1, s1, c1);
        f32x4 o = {s0, c0, s1, c1};
        // Block writes 2 contiguous rows (4 KiB) per iter, marching through
        // its disjoint 256 KiB output region. NT store (round 10/11 A/B:
        // NT 213us beats cached 244us).
        f32x4* dst = reinterpret_cast<f32x4*>(out + (size_t)(base + r) * VEC) + q;
        __builtin_nontemporal_store(o, dst);
    }
}

extern "C" void kernel_launch(void* const* d_in, const int* in_sizes, int n_in,
                              void* d_out, int out_size, void* d_ws, size_t ws_size,
                              hipStream_t stream) {
    const float* x = (const float*)d_in[0];
    float* out = (float*)d_out;
    input_layer_kernel<<<BATCH / RPB, 256, 0, stream>>>(x, out);
}

// Round 13
// 195.227 us; speedup vs baseline: 1.2485x; 1.0320x over previous
//
#include <hip/hip_runtime.h>
#include <math.h>

#define BATCH 524288
#define VEC 512
#define RPB 128   // contiguous rows per block; 4096 blocks x 128 rows = 524288

typedef float f32x4 __attribute__((ext_vector_type(4)));

// Accurate sincos of an f32 phase value: f64 reduction by pi/2 of the exact
// f32 input, then f32 minimax kernels on [-pi/4, pi/4] (~1e-7 abs error).
// Correctness-proven in round 10 (absmax 3.9e-3). DO NOT change.
__device__ __forceinline__ void sincos_acc(float phf, float& s, float& c) {
    const double two_over_pi = 0.6366197723675814;
    const double pio2        = 1.5707963267948966;
    const double ph  = (double)phf;                 // exact
    const double nd  = rint(ph * two_over_pi);      // |nd| <= ~3.4e4, exact int
    const double red = fma(-nd, pio2, ph);          // |red| <= pi/4, err ~1e-12
    const int    q   = ((int)nd) & 3;               // correct for negative nd
    const float  r   = (float)red;
    const float  r2  = r * r;
    float sp = fmaf(r2, 2.7183114939898219e-6f, -1.9839334836096632e-4f);
    sp = fmaf(r2, sp, 8.3333293858894632e-3f);
    sp = fmaf(r2, sp, -1.6666666641626524e-1f);
    sp = r * fmaf(r2, sp, 1.0f);
    float cp = fmaf(r2, 2.4390448796277409e-5f, -1.3886763774609929e-3f);
    cp = fmaf(r2, cp, 4.1666623323739063e-2f);
    cp = fmaf(r2, cp, -4.9999999725103100e-1f);
    cp = fmaf(r2, cp, 1.0f);
    const bool swp = (q & 1);
    float ss = swp ? cp : sp;
    float cc = swp ? sp : cp;
    s = (q & 2)       ? -ss : ss;
    c = ((q + 1) & 2) ? -cc : cc;
}

__global__ __launch_bounds__(256) void input_layer_kernel(const float* __restrict__ x,
                                                          float* __restrict__ out) {
    __shared__ float xs[RPB];
    const int tid  = threadIdx.x;
    const int base = blockIdx.x * RPB;          // this block's contiguous row range

    // One-time x stage: 128 floats = 512 B coalesced. Hot loop does ZERO
    // global reads -- pure write stream like fillBuffer.
    if (tid < RPB) xs[tid] = x[base + tid];

    // FREQUENCY CHAIN -- correctness-critical, verified round 10 (absmax 3.9e-3):
    // ref e-chain = fast-math reciprocal division (XLA:CPU arcp):
    //   e = (i * fl32(1/255)) * 4, NOT true f32 division.
    // pow = accurate exp10 -> matched by CR f64 pow. DO NOT change.
    const int   q      = tid & 127;             // float4 index within row
    const float RCP255 = 1.0f / 255.0f;         // compile-time fl32(1/255)
    const float e0 = ((float)(2 * q)     * RCP255) * 4.0f;
    const float e1 = ((float)(2 * q + 1) * RCP255) * 4.0f;
    const float f0 = (float)pow(10.0, (double)e0);
    const float f1 = (float)pow(10.0, (double)e1);

    __syncthreads();

    const int half = tid >> 7;                  // 0 or 1: which of the 2 rows/iter
    for (int k = 0; k < RPB; k += 2) {
        const int   r  = k + half;              // wave-uniform -> LDS broadcast read
        const float xv = xs[r];
        float s0, c0, s1, c1;
        sincos_acc(xv * f0, s0, c0);            // phase rounded to f32, like the ref
        sincos_acc(xv * f1, s1, c1);
        f32x4 o = {s0, c0, s1, c1};
        // A/B vs R12 (single variable): CACHED store in the read-free
        // structure. fillBuffer = cached + read-free = 6.6 TB/s; R11's
        // cached regression was confounded by the x-read stream in L2.
        // Full-line wave-coverage (1 KiB contiguous per store) -> no RFO.
        f32x4* dst = reinterpret_cast<f32x4*>(out + (size_t)(base + r) * VEC) + q;
        *dst = o;
    }
}

extern "C" void kernel_launch(void* const* d_in, const int* in_sizes, int n_in,
                              void* d_out, int out_size, void* d_ws, size_t ws_size,
                              hipStream_t stream) {
    const float* x = (const float*)d_in[0];
    float* out = (float*)d_out;
    input_layer_kernel<<<BATCH / RPB, 256, 0, stream>>>(x, out);
}

// Round 14
// 194.967 us; speedup vs baseline: 1.2501x; 1.0013x over previous
//
#include <hip/hip_runtime.h>
#include <math.h>

#define BATCH 524288
#define VEC 512
#define RPB 128   // contiguous rows per block; 4096 blocks x 128 rows = 524288

typedef float f32x4 __attribute__((ext_vector_type(4)));

// Accurate sincos of an f32 phase value: f64 reduction by pi/2 of the exact
// f32 input, then f32 minimax kernels on [-pi/4, pi/4] (~1e-7 abs error).
// Correctness-proven in round 10 (absmax 3.9e-3). DO NOT change.
__device__ __forceinline__ void sincos_acc(float phf, float& s, float& c) {
    const double two_over_pi = 0.6366197723675814;
    const double pio2        = 1.5707963267948966;
    const double ph  = (double)phf;                 // exact
    const double nd  = rint(ph * two_over_pi);      // |nd| <= ~3.4e4, exact int
    const double red = fma(-nd, pio2, ph);          // |red| <= pi/4, err ~1e-12
    const int    q   = ((int)nd) & 3;               // correct for negative nd
    const float  r   = (float)red;
    const float  r2  = r * r;
    float sp = fmaf(r2, 2.7183114939898219e-6f, -1.9839334836096632e-4f);
    sp = fmaf(r2, sp, 8.3333293858894632e-3f);
    sp = fmaf(r2, sp, -1.6666666641626524e-1f);
    sp = r * fmaf(r2, sp, 1.0f);
    float cp = fmaf(r2, 2.4390448796277409e-5f, -1.3886763774609929e-3f);
    cp = fmaf(r2, cp, 4.1666623323739063e-2f);
    cp = fmaf(r2, cp, -4.9999999725103100e-1f);
    cp = fmaf(r2, cp, 1.0f);
    const bool swp = (q & 1);
    float ss = swp ? cp : sp;
    float cc = swp ? sp : cp;
    s = (q & 2)       ? -ss : ss;
    c = ((q + 1) & 2) ? -cc : cc;
}

__global__ __launch_bounds__(256) void input_layer_kernel(const float* __restrict__ x,
                                                          float* __restrict__ out) {
    __shared__ float xs[RPB];
    const int tid  = threadIdx.x;
    const int base = blockIdx.x * RPB;          // this block's contiguous row range

    // One-time x stage: 128 floats = 512 B coalesced. Hot loop does ZERO
    // global reads -- pure write stream like fillBuffer.
    if (tid < RPB) xs[tid] = x[base + tid];

    // FREQUENCY CHAIN -- correctness-critical, verified round 10 (absmax 3.9e-3):
    // ref e-chain = fast-math reciprocal division (XLA:CPU arcp):
    //   e = (i * fl32(1/255)) * 4, NOT true f32 division.
    // pow = accurate exp10 -> matched by CR f64 pow. DO NOT change.
    const int   q      = tid & 127;             // float4 index within row
    const float RCP255 = 1.0f / 255.0f;         // compile-time fl32(1/255)
    const float e0 = ((float)(2 * q)     * RCP255) * 4.0f;
    const float e1 = ((float)(2 * q + 1) * RCP255) * 4.0f;
    const float f0 = (float)pow(10.0, (double)e0);
    const float f1 = (float)pow(10.0, (double)e1);

    __syncthreads();

    const int half = tid >> 7;                  // 0 or 1: which row pair member
    for (int k = 0; k < RPB; k += 4) {
        // Unroll x2 across rows: two INDEPENDENT sincos chains + two
        // back-to-back dwordx4 stores per thread per iteration.
        // A/B vs R13 (store-issue-density theory): only this changed.
        const int   ra = k + half;              // rows k / k+1
        const int   rb = k + 2 + half;          // rows k+2 / k+3
        const float xa = xs[ra];
        const float xb = xs[rb];
        float sa0, ca0, sa1, ca1, sb0, cb0, sb1, cb1;
        sincos_acc(xa * f0, sa0, ca0);
        sincos_acc(xb * f0, sb0, cb0);
        sincos_acc(xa * f1, sa1, ca1);
        sincos_acc(xb * f1, sb1, cb1);
        f32x4 oa = {sa0, ca0, sa1, ca1};
        f32x4 ob = {sb0, cb0, sb1, cb1};
        f32x4* da = reinterpret_cast<f32x4*>(out + (size_t)(base + ra) * VEC) + q;
        f32x4* db = reinterpret_cast<f32x4*>(out + (size_t)(base + rb) * VEC) + q;
        *da = oa;                               // cached stores (R13 A/B winner)
        *db = ob;
    }
}

extern "C" void kernel_launch(void* const* d_in, const int* in_sizes, int n_in,
                              void* d_out, int out_size, void* d_ws, size_t ws_size,
                              hipStream_t stream) {
    const float* x = (const float*)d_in[0];
    float* out = (float*)d_out;
    input_layer_kernel<<<BATCH / RPB, 256, 0, stream>>>(x, out);
}